// Round 6
// baseline (347.932 us; speedup 1.0000x reference)
//
#include <hip/hip_runtime.h>
#include <math.h>

#define B 16
#define CIN 512
#define COUT 512
#define SDIM 512
#define H 64
#define W 64

typedef short s16x8 __attribute__((ext_vector_type(8)));
typedef float f32x4 __attribute__((ext_vector_type(4)));
typedef float f32x16 __attribute__((ext_vector_type(16)));

__device__ __constant__ float LIN_SCALE  = 0.04419417382415922f;   // 1/sqrt(512)
__device__ __constant__ float CONV_SCALE = 0.014731391274719742f;  // 1/sqrt(512*9)

__device__ __forceinline__ ushort f2bf(float f) {
  unsigned u = __float_as_uint(f);
  return (ushort)((u + 0x7FFFu + ((u >> 16) & 1u)) >> 16);  // RNE
}

#define GLOAD16(g, l)                                           \
  __builtin_amdgcn_global_load_lds(                             \
      (const __attribute__((address_space(1))) unsigned*)(g),   \
      (__attribute__((address_space(3))) unsigned*)(l), 16, 0, 0)

// ---------------------------------------------------------------------------
// Kernel 1: s[b,ci] = style[b,:] . style_w[ci,:] * lin_scale + style_b[ci]
// ---------------------------------------------------------------------------
__global__ __launch_bounds__(512) void style_mod_kernel(
    const float* __restrict__ style, const float* __restrict__ style_w,
    const float* __restrict__ style_b, float* __restrict__ s,
    float* __restrict__ s2) {
  const int b = blockIdx.x;
  const int ci = threadIdx.x;
  __shared__ float st[SDIM];
  st[ci] = style[b * SDIM + ci];
  __syncthreads();

  const float4* wr = reinterpret_cast<const float4*>(style_w + (size_t)ci * SDIM);
  float acc = 0.f;
#pragma unroll 4
  for (int k = 0; k < SDIM / 4; ++k) {
    float4 wv = wr[k];
    acc += st[4 * k + 0] * wv.x + st[4 * k + 1] * wv.y +
           st[4 * k + 2] * wv.z + st[4 * k + 3] * wv.w;
  }
  float v = acc * LIN_SCALE + style_b[ci];
  s[b * CIN + ci] = v;
  s2[b * CIN + ci] = v * v;
}

// ---------------------------------------------------------------------------
// Kernel 2: wsq[co,ci] = sum_k weight[co,ci,k]^2
// ---------------------------------------------------------------------------
__global__ __launch_bounds__(256) void wsq_kernel(
    const float* __restrict__ weight, float* __restrict__ wsq) {
  const int i = blockIdx.x * blockDim.x + threadIdx.x;
  if (i >= COUT * CIN) return;
  const float* p = weight + (size_t)i * 9;
  float a = 0.f;
#pragma unroll
  for (int k = 0; k < 9; ++k) {
    float v = p[k];
    a += v * v;
  }
  wsq[i] = a;
}

// ---------------------------------------------------------------------------
// Kernel 3: outscale[b,co] = conv_scale * rsqrt(conv_scale^2 * sum + 1e-8)
// ---------------------------------------------------------------------------
__global__ __launch_bounds__(512) void dcoef_kernel(
    const float* __restrict__ s2, const float* __restrict__ wsq,
    float* __restrict__ outscale) {
  const int b = blockIdx.x;
  const int co = threadIdx.x;
  __shared__ float sh[CIN];
  sh[co] = s2[b * CIN + co];
  __syncthreads();

  const float4* wr = reinterpret_cast<const float4*>(wsq + (size_t)co * CIN);
  float acc = 0.f;
#pragma unroll 4
  for (int k = 0; k < CIN / 4; ++k) {
    float4 wv = wr[k];
    acc += sh[4 * k + 0] * wv.x + sh[4 * k + 1] * wv.y +
           sh[4 * k + 2] * wv.z + sh[4 * k + 3] * wv.w;
  }
  float d = rsqrtf(acc * CONV_SCALE * CONV_SCALE + 1e-8f);
  outscale[b * COUT + co] = d * CONV_SCALE;
}

// ---------------------------------------------------------------------------
// Kernel P1: pack weights -> wt[chunk][j][co][slot][8ci] bf16,
// slot = s ^ ((co>>1)&3)  (bank swizzle baked into global layout).
// Byte strides: chunk 294912, j 32768, co 64, slot 16.
// ---------------------------------------------------------------------------
__global__ __launch_bounds__(256) void pack_w_kernel(
    const float* __restrict__ w, ushort* __restrict__ wt) {
  const int t = blockIdx.x * 256 + threadIdx.x;  // 32768 threads
  const int s = t & 3;
  const int chunk = (t >> 2) & 15;
  const int co = t >> 6;
  const float4* wp =
      (const float4*)(w + ((size_t)co * 512 + chunk * 32 + s * 8) * 9);
  float wv[72];
#pragma unroll
  for (int i = 0; i < 18; ++i) {
    float4 v = wp[i];
    wv[4 * i + 0] = v.x; wv[4 * i + 1] = v.y;
    wv[4 * i + 2] = v.z; wv[4 * i + 3] = v.w;
  }
  const int sp = s ^ ((co >> 1) & 3);
  ushort* dst = wt + (size_t)chunk * 147456 + (size_t)co * 32 + sp * 8;
#pragma unroll
  for (int j = 0; j < 9; ++j) {
    s16x8 p;
#pragma unroll
    for (int i = 0; i < 8; ++i) p[i] = (short)f2bf(wv[i * 9 + j]);
    *(s16x8*)(dst + (size_t)j * 16384) = p;
  }
}

// ---------------------------------------------------------------------------
// Kernel P2: pack x -> xp[b][chunk][gr][c][slot][8ci] bf16, s folded in;
// slot = s ^ (((c+1)>>1)&3). Byte strides: (b,chunk) 262144, gr 4096, c 64.
// ---------------------------------------------------------------------------
__global__ __launch_bounds__(256) void pack_x_kernel(
    const float* __restrict__ x, const float* __restrict__ smod,
    ushort* __restrict__ xp) {
  __shared__ float xt[32][65];
  __shared__ float sm[32];
  const int tid = threadIdx.x;
  const int gr = blockIdx.x, chunk = blockIdx.y, b = blockIdx.z;
  if (tid < 32) sm[tid] = smod[b * 512 + chunk * 32 + tid];
  {
    const int ci = tid >> 3, cq = tid & 7;
    const float4* rp = (const float4*)(
        x + (((size_t)b * 512 + chunk * 32 + ci) * 64 + gr) * 64 + cq * 8);
    float4 a = rp[0], c2 = rp[1];
    float* row = &xt[ci][cq * 8];
    row[0] = a.x; row[1] = a.y; row[2] = a.z; row[3] = a.w;
    row[4] = c2.x; row[5] = c2.y; row[6] = c2.z; row[7] = c2.w;
  }
  __syncthreads();
  const int c = tid >> 2, s = tid & 3;
  s16x8 p;
#pragma unroll
  for (int i = 0; i < 8; ++i)
    p[i] = (short)f2bf(xt[s * 8 + i][c] * sm[s * 8 + i]);
  const int sp = s ^ (((c + 1) >> 1) & 3);
  *(s16x8*)(xp + ((size_t)(b * 16 + chunk) * 64 + gr) * 2048 + c * 32 + sp * 8) = p;
}

// ---------------------------------------------------------------------------
// Kernel 5: 32x32x16 MFMA conv with cross-kh B-frag caching.
// 256 thr / 4 waves; tile 64 co x 8 rows x 64 px; wave wid owns rows
// h0+2wid, h0+2wid+1. Wave frags: 2 mt (32 co) x 2 nt (32 px) x 2 rr.
// Per chunk (kw-outer): 48 B-reads (4 rows x 2 nt x 2 ks, cached across kh)
// + 36 A-reads -> 144 mfma_f32_32x32x16_bf16. 84 ds_read_b128 / chunk / wave.
// A-frag: lane l = co(l&31), ci octet (l>>5)+2ks, phys slot ^((co>>1)&3).
// B-frag: lane l = col(l&31)+nt*32+kw, same slot scheme.
// D: col(px)=lane&31, row(co)=(reg&3)+8*(reg>>2)+4*(lane>>5)  [m74/m101].
// Dynamic LDS 79104 B: ws[9][64][32] @0, xs[10][66][32] @36864. 2 blocks/CU.
// ---------------------------------------------------------------------------
#define XS4OFF 36864
#define DLDS4 79104

__global__ __launch_bounds__(256, 2) void conv_mfma5_kernel(
    const ushort* __restrict__ wt, const ushort* __restrict__ xp,
    const float* __restrict__ outscale, float* __restrict__ out) {
  extern __shared__ char smem[];

  const int tid = threadIdx.x;
  const int hb = blockIdx.x;  // 0..7
  const int cb = blockIdx.y;  // 0..7
  const int b  = blockIdx.z;  // 0..15
  const int h0 = hb * 8, co0 = cb * 64;
  const int lane = tid & 63, wid = tid >> 6;  // 4 waves
  const int l31 = lane & 31, hi = lane >> 5;

  // zero xs buffer once: halo cols 0/65 + OOB edge rows stay zero all chunks
  {
    s16x8* p = (s16x8*)(smem + XS4OFF);
    for (int e = tid; e < 2640; e += 256) p[e] = (s16x8)0;
  }

  f32x16 acc[2][2][2];
#pragma unroll
  for (int rr = 0; rr < 2; ++rr)
#pragma unroll
    for (int mt = 0; mt < 2; ++mt)
#pragma unroll
      for (int nt = 0; nt < 2; ++nt) acc[rr][mt][nt] = (f32x16)0.f;

  // loop-invariant swizzled byte offsets
  const int akey = (l31 >> 1) & 3;
  int aoff[2][2];  // [mt][ks]
#pragma unroll
  for (int mt = 0; mt < 2; ++mt)
#pragma unroll
    for (int ks = 0; ks < 2; ++ks)
      aoff[mt][ks] = (mt * 32 + l31) * 64 + ((ks * 2 + hi) ^ akey) * 16;

  int boff[3][2][2];  // [kw][nt][ks]
#pragma unroll
  for (int kw = 0; kw < 3; ++kw)
#pragma unroll
    for (int nt = 0; nt < 2; ++nt)
#pragma unroll
      for (int ks = 0; ks < 2; ++ks) {
        int cc = nt * 32 + l31 + kw;
        boff[kw][nt][ks] = cc * 64 + (((ks * 2 + hi) ^ ((cc >> 1) & 3))) * 16;
      }

  const char* wsrc0 = (const char*)wt + cb * 4096 + tid * 16;
  const char* xsrc0 = (const char*)xp + (size_t)b * 4194304 + tid * 16;
  char* wdst = smem + tid * 16;
  char* xdst = smem + XS4OFF + 64 + tid * 16;
  const char* wb = smem;
  const char* xb = smem + XS4OFF + 2 * wid * 4224;  // wave's top xs row

  __syncthreads();  // zero visible

  for (int chunk = 0; chunk < 16; ++chunk) {
    const char* wsrc = wsrc0 + (size_t)chunk * 294912;
    const char* xsrc = xsrc0 + (size_t)chunk * 262144;
#pragma unroll
    for (int t = 0; t < 9; ++t)
      GLOAD16(wsrc + t * 32768, wdst + t * 4096);
#pragma unroll
    for (int t = 0; t < 10; ++t) {
      int gr = h0 - 1 + t;
      if ((unsigned)gr < 64u)
        GLOAD16(xsrc + (size_t)gr * 4096, xdst + t * 4224);
    }
    __syncthreads();  // staged data visible

#pragma unroll
    for (int kw = 0; kw < 3; ++kw) {
      // cache B-frags for this kw: 4 rows x 2 nt x 2 ks
      s16x8 bf[4][2][2];
#pragma unroll
      for (int q = 0; q < 4; ++q)
#pragma unroll
        for (int nt = 0; nt < 2; ++nt)
#pragma unroll
          for (int ks = 0; ks < 2; ++ks)
            bf[q][nt][ks] =
                *(const s16x8*)(xb + q * 4224 + boff[kw][nt][ks]);
#pragma unroll
      for (int kh = 0; kh < 3; ++kh) {
        const char* wj = wb + (kh * 3 + kw) * 4096;
#pragma unroll
        for (int ks = 0; ks < 2; ++ks) {
          s16x8 af0 = *(const s16x8*)(wj + aoff[0][ks]);
          s16x8 af1 = *(const s16x8*)(wj + aoff[1][ks]);
#pragma unroll
          for (int rr = 0; rr < 2; ++rr)
#pragma unroll
            for (int nt = 0; nt < 2; ++nt) {
              acc[rr][0][nt] = __builtin_amdgcn_mfma_f32_32x32x16_bf16(
                  af0, bf[rr + kh][nt][ks], acc[rr][0][nt], 0, 0, 0);
              acc[rr][1][nt] = __builtin_amdgcn_mfma_f32_32x32x16_bf16(
                  af1, bf[rr + kh][nt][ks], acc[rr][1][nt], 0, 0, 0);
            }
        }
      }
    }
    __syncthreads();  // protect LDS before next chunk's staging
  }

  // epilogue: D col(px)=l31, row(co)=(reg&3)+8*(reg>>2)+4*hi
#pragma unroll
  for (int mt = 0; mt < 2; ++mt) {
#pragma unroll
    for (int reg = 0; reg < 16; ++reg) {
      const int row = (reg & 3) + 8 * (reg >> 2) + 4 * hi;
      const int co = co0 + mt * 32 + row;
      const float osc = outscale[b * COUT + co];
      float* obase = out + ((size_t)b * COUT + co) * H * W;
#pragma unroll
      for (int rr = 0; rr < 2; ++rr) {
        const int h = h0 + 2 * wid + rr;
#pragma unroll
        for (int nt = 0; nt < 2; ++nt)
          obase[h * W + nt * 32 + l31] = acc[rr][mt][nt][reg] * osc;
      }
    }
  }
}

// ---------------------------------------------------------------------------
// Fallback conv (R3, proven): 2-phase, static LDS, 2 blocks/CU, 1 row/wave.
// ---------------------------------------------------------------------------
__global__ __launch_bounds__(256, 2) void conv_mfma2_kernel(
    const ushort* __restrict__ wt, const ushort* __restrict__ xp,
    const float* __restrict__ outscale, float* __restrict__ out) {
  __shared__ ushort ws[9][64][32];
  __shared__ ushort xs[6][66][32];

  const int tid = threadIdx.x;
  const int hb = blockIdx.x, cb = blockIdx.y, b = blockIdx.z;
  const int h0 = hb * 4, co0 = cb * 64;
  const int lane = tid & 63, wid = tid >> 6;
  const int l15 = lane & 15, l4 = lane >> 4;

  {
    s16x8* p = (s16x8*)&xs[0][0][0];
    for (int e = tid; e < 1584; e += 256) p[e] = (s16x8)0;
  }

  f32x4 acc[4][4];
#pragma unroll
  for (int mt = 0; mt < 4; ++mt)
#pragma unroll
    for (int nt = 0; nt < 4; ++nt) acc[mt][nt] = (f32x4)0.f;

  const int am = (l4 ^ ((l15 >> 1) & 3)) * 16;
  int aoff[4];
#pragma unroll
  for (int mt = 0; mt < 4; ++mt) aoff[mt] = (mt * 16 + l15) * 64 + am;
  int boff[12];
#pragma unroll
  for (int nt = 0; nt < 4; ++nt)
#pragma unroll
    for (int kw = 0; kw < 3; ++kw) {
      int col = nt * 16 + l15 + kw;
      boff[nt * 3 + kw] =
          wid * 4224 + col * 64 + ((l4 ^ ((col >> 1) & 3)) * 16);
    }

  const char* wsrc0 = (const char*)wt + cb * 4096 + wid * 1024 + lane * 16;
  const char* xsrc0 =
      (const char*)xp + (size_t)b * 4194304 + wid * 1024 + lane * 16;
  char* wdst = (char*)&ws[0][0][0] + wid * 1024 + lane * 16;
  char* xdst = (char*)&xs[0][0][0] + 64 + wid * 1024 + lane * 16;

  __syncthreads();

  for (int chunk = 0; chunk < 16; ++chunk) {
    const char* wsrc = wsrc0 + chunk * 294912;
    const char* xsrc = xsrc0 + chunk * 262144;
#pragma unroll
    for (int t = 0; t < 9; ++t)
      GLOAD16(wsrc + t * 32768, wdst + t * 4096);
#pragma unroll
    for (int t = 0; t < 6; ++t) {
      int gr = h0 - 1 + t;
      if ((unsigned)gr < 64u) GLOAD16(xsrc + gr * 4096, xdst + t * 4224);
    }
    __syncthreads();

#pragma unroll
    for (int kh = 0; kh < 3; ++kh) {
      const char* xrow = (const char*)&xs[0][0][0] + kh * 4224;
#pragma unroll
      for (int kw = 0; kw < 3; ++kw) {
        const int j = kh * 3 + kw;
        const char* wj = (const char*)&ws[0][0][0] + j * 4096;
        s16x8 af[4], bf[4];
#pragma unroll
        for (int mt = 0; mt < 4; ++mt)
          af[mt] = *(const s16x8*)(wj + aoff[mt]);
#pragma unroll
        for (int nt = 0; nt < 4; ++nt)
          bf[nt] = *(const s16x8*)(xrow + boff[nt * 3 + kw]);
#pragma unroll
        for (int mt = 0; mt < 4; ++mt)
#pragma unroll
          for (int nt = 0; nt < 4; ++nt)
            acc[mt][nt] = __builtin_amdgcn_mfma_f32_16x16x32_bf16(
                af[mt], bf[nt], acc[mt][nt], 0, 0, 0);
      }
    }
    __syncthreads();
  }

  const int h = h0 + wid;
#pragma unroll
  for (int mt = 0; mt < 4; ++mt) {
#pragma unroll
    for (int r = 0; r < 4; ++r) {
      const int co = co0 + mt * 16 + l4 * 4 + r;
      const float osc = outscale[b * COUT + co];
      float* orow = out + (((size_t)b * COUT + co) * H + h) * W;
#pragma unroll
      for (int nt = 0; nt < 4; ++nt)
        orow[nt * 16 + l15] = acc[mt][nt][r] * osc;
    }
  }
}

// ---------------------------------------------------------------------------
extern "C" void kernel_launch(void* const* d_in, const int* in_sizes, int n_in,
                              void* d_out, int out_size, void* d_ws,
                              size_t ws_size, hipStream_t stream) {
  const float* x = (const float*)d_in[0];
  const float* style = (const float*)d_in[1];
  const float* weight = (const float*)d_in[2];
  const float* style_w = (const float*)d_in[3];
  const float* style_b = (const float*)d_in[4];
  float* out = (float*)d_out;

  // workspace layout (bytes):
  //   0        s        (32768)
  //   32768    s2       (32768)
  //   65536    wsq      (1048576)
  //   1114112  outscale (32768)
  //   1146880  wt       (4718592)   packed bf16 weights
  //   5865472  xp       (67108864)  packed bf16 x (s folded)
  char* wsb = (char*)d_ws;
  float* s = (float*)(wsb + 0);
  float* s2 = (float*)(wsb + 32768);
  float* wsq = (float*)(wsb + 65536);
  float* outscale = (float*)(wsb + 1114112);
  ushort* wt = (ushort*)(wsb + 1146880);
  ushort* xp = (ushort*)(wsb + 5865472);
  const size_t NEED = 72974336;

  style_mod_kernel<<<B, 512, 0, stream>>>(style, style_w, style_b, s, s2);
  wsq_kernel<<<(COUT * CIN + 255) / 256, 256, 0, stream>>>(weight, wsq);
  dcoef_kernel<<<B, 512, 0, stream>>>(s2, wsq, outscale);

  pack_w_kernel<<<128, 256, 0, stream>>>(weight, wt);
  pack_x_kernel<<<dim3(64, 16, 16), 256, 0, stream>>>(x, s, xp);

  hipError_t attr_ok = hipFuncSetAttribute(
      reinterpret_cast<const void*>(conv_mfma5_kernel),
      hipFuncAttributeMaxDynamicSharedMemorySize, DLDS4);

  if (attr_ok == hipSuccess && ws_size >= NEED) {
    conv_mfma5_kernel<<<dim3(8, 8, 16), 256, DLDS4, stream>>>(wt, xp, outscale,
                                                              out);
  } else {
    conv_mfma2_kernel<<<dim3(16, 8, 16), 256, 0, stream>>>(wt, xp, outscale,
                                                           out);
  }
}

// Round 7
// 345.428 us; speedup vs baseline: 1.0072x; 1.0072x over previous
//
#include <hip/hip_runtime.h>
#include <math.h>

#define B 16
#define CIN 512
#define COUT 512
#define SDIM 512
#define H 64
#define W 64

typedef short s16x8 __attribute__((ext_vector_type(8)));
typedef float f32x4 __attribute__((ext_vector_type(4)));
typedef float f32x16 __attribute__((ext_vector_type(16)));

__device__ __constant__ float LIN_SCALE  = 0.04419417382415922f;   // 1/sqrt(512)
__device__ __constant__ float CONV_SCALE = 0.014731391274719742f;  // 1/sqrt(512*9)

__device__ __forceinline__ ushort f2bf(float f) {
  unsigned u = __float_as_uint(f);
  return (ushort)((u + 0x7FFFu + ((u >> 16) & 1u)) >> 16);  // RNE
}

// pair-interleaved slot swizzle: row pair stride 128B, 8 slots of 16B.
// slot(col, octet) = (4*(col&1) + octet) ^ ((col>>1)&7)
// bank = 4*slot + w (pair*128B == 0 mod 32 words) -> row-independent,
// uniform 8 lanes/slot for all conv read patterns => conflict-free b128.
__device__ __forceinline__ int slot_swz(int col, int o) {
  return ((col & 1) * 4 + o) ^ ((col >> 1) & 7);
}

#define GLOAD16(g, l)                                           \
  __builtin_amdgcn_global_load_lds(                             \
      (const __attribute__((address_space(1))) unsigned*)(g),   \
      (__attribute__((address_space(3))) unsigned*)(l), 16, 0, 0)

// ---------------------------------------------------------------------------
// Kernel 1: s[b,ci] = style[b,:] . style_w[ci,:] * lin_scale + style_b[ci]
// ---------------------------------------------------------------------------
__global__ __launch_bounds__(512) void style_mod_kernel(
    const float* __restrict__ style, const float* __restrict__ style_w,
    const float* __restrict__ style_b, float* __restrict__ s,
    float* __restrict__ s2) {
  const int b = blockIdx.x;
  const int ci = threadIdx.x;
  __shared__ float st[SDIM];
  st[ci] = style[b * SDIM + ci];
  __syncthreads();

  const float4* wr = reinterpret_cast<const float4*>(style_w + (size_t)ci * SDIM);
  float acc = 0.f;
#pragma unroll 4
  for (int k = 0; k < SDIM / 4; ++k) {
    float4 wv = wr[k];
    acc += st[4 * k + 0] * wv.x + st[4 * k + 1] * wv.y +
           st[4 * k + 2] * wv.z + st[4 * k + 3] * wv.w;
  }
  float v = acc * LIN_SCALE + style_b[ci];
  s[b * CIN + ci] = v;
  s2[b * CIN + ci] = v * v;
}

// ---------------------------------------------------------------------------
// Kernel 3: outscale[b,co] = conv_scale * rsqrt(conv_scale^2 * sum + 1e-8)
// ---------------------------------------------------------------------------
__global__ __launch_bounds__(512) void dcoef_kernel(
    const float* __restrict__ s2, const float* __restrict__ wsq,
    float* __restrict__ outscale) {
  const int b = blockIdx.x;
  const int co = threadIdx.x;
  __shared__ float sh[CIN];
  sh[co] = s2[b * CIN + co];
  __syncthreads();

  const float4* wr = reinterpret_cast<const float4*>(wsq + (size_t)co * CIN);
  float acc = 0.f;
#pragma unroll 4
  for (int k = 0; k < CIN / 4; ++k) {
    float4 wv = wr[k];
    acc += sh[4 * k + 0] * wv.x + sh[4 * k + 1] * wv.y +
           sh[4 * k + 2] * wv.z + sh[4 * k + 3] * wv.w;
  }
  float d = rsqrtf(acc * CONV_SCALE * CONV_SCALE + 1e-8f);
  outscale[b * COUT + co] = d * CONV_SCALE;
}

// ---------------------------------------------------------------------------
// Kernel P1 (fused wsq): pack weights -> wt[chunk][j][co-pair][slot][8ci]
// with slot = slot_swz(co, octet); also writes wsq[co][ci] = sum_k w^2.
// Byte strides: chunk 294912, j 32768, co-pair 128, slot 16.
// ---------------------------------------------------------------------------
__global__ __launch_bounds__(256) void pack_w_kernel(
    const float* __restrict__ w, ushort* __restrict__ wt,
    float* __restrict__ wsq) {
  const int t = blockIdx.x * 256 + threadIdx.x;  // 32768 threads
  const int s = t & 3;                           // ci octet
  const int chunk = (t >> 2) & 15;
  const int co = t >> 6;                         // global co
  const float4* wp =
      (const float4*)(w + ((size_t)co * 512 + chunk * 32 + s * 8) * 9);
  float wv[72];
#pragma unroll
  for (int i = 0; i < 18; ++i) {
    float4 v = wp[i];
    wv[4 * i + 0] = v.x; wv[4 * i + 1] = v.y;
    wv[4 * i + 2] = v.z; wv[4 * i + 3] = v.w;
  }
  // wsq fused: per-ci sum over 9 taps
  {
    float q[8];
#pragma unroll
    for (int i = 0; i < 8; ++i) {
      float a = 0.f;
#pragma unroll
      for (int k = 0; k < 9; ++k) {
        float v = wv[i * 9 + k];
        a += v * v;
      }
      q[i] = a;
    }
    float4* qd = (float4*)(wsq + (size_t)co * 512 + chunk * 32 + s * 8);
    qd[0] = make_float4(q[0], q[1], q[2], q[3]);
    qd[1] = make_float4(q[4], q[5], q[6], q[7]);
  }
  const int sp = slot_swz(co, s);
  ushort* dst = wt + (size_t)chunk * 147456 + (size_t)(co >> 1) * 64 + sp * 8;
#pragma unroll
  for (int j = 0; j < 9; ++j) {
    s16x8 p;
#pragma unroll
    for (int i = 0; i < 8; ++i) p[i] = (short)f2bf(wv[i * 9 + j]);
    *(s16x8*)(dst + (size_t)j * 16384) = p;
  }
}

// ---------------------------------------------------------------------------
// Kernel P2: pack x -> xp[b][chunk][gr][...] bf16, s folded in.
// LDS col cc = gc+1; in-row byte = (cc>>1)*128 + slot_swz(cc,o)*16; global
// stores bytes [64, 4160) of the 4224B LDS row as a 4096B run (halo halves
// of pairs 0 and 32 stay zero in LDS). Strides: (b,chunk) 262144, gr 4096.
// ---------------------------------------------------------------------------
__global__ __launch_bounds__(256) void pack_x_kernel(
    const float* __restrict__ x, const float* __restrict__ smod,
    ushort* __restrict__ xp) {
  __shared__ float xt[32][65];
  __shared__ float sm[32];
  const int tid = threadIdx.x;
  const int gr = blockIdx.x, chunk = blockIdx.y, b = blockIdx.z;
  if (tid < 32) sm[tid] = smod[b * 512 + chunk * 32 + tid];
  {
    const int ci = tid >> 3, cq = tid & 7;
    const float4* rp = (const float4*)(
        x + (((size_t)b * 512 + chunk * 32 + ci) * 64 + gr) * 64 + cq * 8);
    float4 a = rp[0], c2 = rp[1];
    float* row = &xt[ci][cq * 8];
    row[0] = a.x; row[1] = a.y; row[2] = a.z; row[3] = a.w;
    row[4] = c2.x; row[5] = c2.y; row[6] = c2.z; row[7] = c2.w;
  }
  __syncthreads();
  const int c = tid >> 2, o = tid & 3;  // gc = c, ci octet = o
  s16x8 p;
#pragma unroll
  for (int i = 0; i < 8; ++i)
    p[i] = (short)f2bf(xt[o * 8 + i][c] * sm[o * 8 + i]);
  const int cc = c + 1;
  const int off_us = (cc >> 1) * 64 + slot_swz(cc, o) * 8 - 32;  // -64B base
  *(s16x8*)(xp + ((size_t)(b * 16 + chunk) * 64 + gr) * 2048 + off_us) = p;
}

// ---------------------------------------------------------------------------
// Kernel 6: 32x32x16 MFMA conv, pair-interleaved conflict-free LDS.
// 256 thr / 4 waves; tile 64 co x 8 rows x 64 px; wave wid owns rows
// h0+2wid, h0+2wid+1. Per chunk (kw-outer, B cached across kh):
// 36 A-reads + 48 B-reads -> 144 mfma_f32_32x32x16_bf16.
// A-frag lane l: co=l&31 (+32mt), k octet = ks*2 + (l>>5).
// B-frag lane l: px=l&31 (+32nt), cc=px+kw, same octet scheme.
// D: col(px)=lane&31, row(co)=(reg&3)+8*(reg>>2)+4*(lane>>5)  [m74/m101].
// Dynamic LDS 79104 B: ws[9][4096] @0, xs[10][4224] @36864. 2 blocks/CU.
// ---------------------------------------------------------------------------
#define XS4OFF 36864
#define DLDS4 79104

__global__ __launch_bounds__(256, 2) void conv_mfma6_kernel(
    const ushort* __restrict__ wt, const ushort* __restrict__ xp,
    const float* __restrict__ outscale, float* __restrict__ out) {
  extern __shared__ char smem[];

  const int tid = threadIdx.x;
  const int hb = blockIdx.x;  // 0..7
  const int cb = blockIdx.y;  // 0..7
  const int b  = blockIdx.z;  // 0..15
  const int h0 = hb * 8, co0 = cb * 64;
  const int lane = tid & 63, wid = tid >> 6;  // 4 waves
  const int l31 = lane & 31, hi = lane >> 5;

  // zero xs buffer once: halo pair-halves + OOB edge rows stay zero
  {
    s16x8* p = (s16x8*)(smem + XS4OFF);
    for (int e = tid; e < 2640; e += 256) p[e] = (s16x8)0;
  }

  f32x16 acc[2][2][2];
#pragma unroll
  for (int rr = 0; rr < 2; ++rr)
#pragma unroll
    for (int mt = 0; mt < 2; ++mt)
#pragma unroll
      for (int nt = 0; nt < 2; ++nt) acc[rr][mt][nt] = (f32x16)0.f;

  // loop-invariant swizzled byte offsets
  int aoff[2][2];  // [mt][ks]
#pragma unroll
  for (int mt = 0; mt < 2; ++mt)
#pragma unroll
    for (int ks = 0; ks < 2; ++ks) {
      int co = mt * 32 + l31;
      aoff[mt][ks] = (co >> 1) * 128 + slot_swz(co, ks * 2 + hi) * 16;
    }
  int boff[3][2][2];  // [kw][nt][ks]
#pragma unroll
  for (int kw = 0; kw < 3; ++kw)
#pragma unroll
    for (int nt = 0; nt < 2; ++nt)
#pragma unroll
      for (int ks = 0; ks < 2; ++ks) {
        int cc = nt * 32 + l31 + kw;
        boff[kw][nt][ks] = (cc >> 1) * 128 + slot_swz(cc, ks * 2 + hi) * 16;
      }

  const char* wsrc0 = (const char*)wt + cb * 4096 + tid * 16;
  const char* xsrc0 = (const char*)xp + (size_t)b * 4194304 + tid * 16;
  char* wdst = smem + tid * 16;
  char* xdst = smem + XS4OFF + 64 + tid * 16;
  const char* wb = smem;
  const char* xb = smem + XS4OFF + 2 * wid * 4224;  // wave's top xs row

  __syncthreads();  // zero visible

  for (int chunk = 0; chunk < 16; ++chunk) {
    const char* wsrc = wsrc0 + (size_t)chunk * 294912;
    const char* xsrc = xsrc0 + (size_t)chunk * 262144;
#pragma unroll
    for (int t = 0; t < 9; ++t)
      GLOAD16(wsrc + t * 32768, wdst + t * 4096);
#pragma unroll
    for (int t = 0; t < 10; ++t) {
      int gr = h0 - 1 + t;
      if ((unsigned)gr < 64u)
        GLOAD16(xsrc + (size_t)gr * 4096, xdst + t * 4224);
    }
    __syncthreads();  // staged data visible

#pragma unroll
    for (int kw = 0; kw < 3; ++kw) {
      // cache B-frags for this kw: 4 rows x 2 nt x 2 ks
      s16x8 bf[4][2][2];
#pragma unroll
      for (int q = 0; q < 4; ++q)
#pragma unroll
        for (int nt = 0; nt < 2; ++nt)
#pragma unroll
          for (int ks = 0; ks < 2; ++ks)
            bf[q][nt][ks] =
                *(const s16x8*)(xb + q * 4224 + boff[kw][nt][ks]);
#pragma unroll
      for (int kh = 0; kh < 3; ++kh) {
        const char* wj = wb + (kh * 3 + kw) * 4096;
#pragma unroll
        for (int ks = 0; ks < 2; ++ks) {
          s16x8 af0 = *(const s16x8*)(wj + aoff[0][ks]);
          s16x8 af1 = *(const s16x8*)(wj + aoff[1][ks]);
#pragma unroll
          for (int rr = 0; rr < 2; ++rr)
#pragma unroll
            for (int nt = 0; nt < 2; ++nt) {
              acc[rr][0][nt] = __builtin_amdgcn_mfma_f32_32x32x16_bf16(
                  af0, bf[rr + kh][nt][ks], acc[rr][0][nt], 0, 0, 0);
              acc[rr][1][nt] = __builtin_amdgcn_mfma_f32_32x32x16_bf16(
                  af1, bf[rr + kh][nt][ks], acc[rr][1][nt], 0, 0, 0);
            }
        }
      }
    }
    __syncthreads();  // protect LDS before next chunk's staging
  }

  // epilogue: D col(px)=l31, row(co)=(reg&3)+8*(reg>>2)+4*hi
#pragma unroll
  for (int mt = 0; mt < 2; ++mt) {
#pragma unroll
    for (int reg = 0; reg < 16; ++reg) {
      const int row = (reg & 3) + 8 * (reg >> 2) + 4 * hi;
      const int co = co0 + mt * 32 + row;
      const float osc = outscale[b * COUT + co];
      float* obase = out + ((size_t)b * COUT + co) * H * W;
#pragma unroll
      for (int rr = 0; rr < 2; ++rr) {
        const int h = h0 + 2 * wid + rr;
#pragma unroll
        for (int nt = 0; nt < 2; ++nt)
          obase[h * W + nt * 32 + l31] = acc[rr][mt][nt][reg] * osc;
      }
    }
  }
}

// ---------------------------------------------------------------------------
// Fallback conv (R2, proven, packless): raw x/weight/s inputs, 630 us.
// Used only if workspace/attr can't support the fast path.
// ---------------------------------------------------------------------------
__global__ __launch_bounds__(256, 2) void conv_mfma_kernel(
    const float* __restrict__ x, const float* __restrict__ weight,
    const float* __restrict__ s, const float* __restrict__ outscale,
    float* __restrict__ out) {
  __shared__ ushort xs[6][66][32];
  __shared__ ushort ws[9][64][32];

  const int tid = threadIdx.x;
  const int hb = blockIdx.x;
  const int cb = blockIdx.y;
  const int b  = blockIdx.z;
  const int h0 = hb * 4;
  const int co0 = cb * 64;
  const int lane = tid & 63;
  const int wid = tid >> 6;
  const int l15 = lane & 15;
  const int l4  = lane >> 4;

  f32x4 acc[4][4];
#pragma unroll
  for (int mt = 0; mt < 4; ++mt)
#pragma unroll
    for (int nt = 0; nt < 4; ++nt) acc[mt][nt] = (f32x4)0.f;

  const int wq = tid & 3;
  const int wco = tid >> 2;

  for (int c0 = 0; c0 < CIN; c0 += 32) {
    {
      const float4* wp = reinterpret_cast<const float4*>(
          weight + ((size_t)(co0 + wco) * CIN + c0 + wq * 8) * 9);
      float wv[72];
#pragma unroll
      for (int t = 0; t < 18; ++t) {
        float4 v = wp[t];
        wv[4 * t + 0] = v.x; wv[4 * t + 1] = v.y;
        wv[4 * t + 2] = v.z; wv[4 * t + 3] = v.w;
      }
      float sv[8];
#pragma unroll
      for (int i = 0; i < 8; ++i) sv[i] = s[b * CIN + c0 + wq * 8 + i];
#pragma unroll
      for (int j = 0; j < 9; ++j) {
        s16x8 p;
#pragma unroll
        for (int i = 0; i < 8; ++i)
          p[i] = (short)f2bf(wv[i * 9 + j] * sv[i]);
        *reinterpret_cast<s16x8*>(&ws[j][wco][wq * 8]) = p;
      }
    }
#pragma unroll
    for (int it = 0; it < 7; ++it) {
      int e = tid + it * 256;
      if (e < 6 * 66 * 4) {
        int q = e & 3;
        int t2 = e >> 2;
        int cc = t2 % 66;
        int r = t2 / 66;
        int gr = h0 - 1 + r;
        int gc = cc - 1;
        s16x8 p;
        if ((unsigned)gr < H && (unsigned)gc < W) {
          const float* xp2 =
              x + (((size_t)b * CIN + c0 + q * 8) * H + gr) * W + gc;
#pragma unroll
          for (int i = 0; i < 8; ++i) p[i] = (short)f2bf(xp2[(size_t)i * H * W]);
        } else {
#pragma unroll
          for (int i = 0; i < 8; ++i) p[i] = 0;
        }
        *reinterpret_cast<s16x8*>(&xs[r][cc][q * 8]) = p;
      }
    }
    __syncthreads();

#pragma unroll
    for (int kh = 0; kh < 3; ++kh) {
#pragma unroll
      for (int kw = 0; kw < 3; ++kw) {
        const int j = kh * 3 + kw;
        s16x8 af[4], bf[4];
#pragma unroll
        for (int mt = 0; mt < 4; ++mt)
          af[mt] = *reinterpret_cast<const s16x8*>(
              &ws[j][mt * 16 + l15][l4 * 8]);
#pragma unroll
        for (int nt = 0; nt < 4; ++nt)
          bf[nt] = *reinterpret_cast<const s16x8*>(
              &xs[wid + kh][nt * 16 + l15 + kw][l4 * 8]);
#pragma unroll
        for (int mt = 0; mt < 4; ++mt)
#pragma unroll
          for (int nt = 0; nt < 4; ++nt)
            acc[mt][nt] = __builtin_amdgcn_mfma_f32_16x16x32_bf16(
                af[mt], bf[nt], acc[mt][nt], 0, 0, 0);
      }
    }
    __syncthreads();
  }

  const int h = h0 + wid;
#pragma unroll
  for (int mt = 0; mt < 4; ++mt) {
#pragma unroll
    for (int r = 0; r < 4; ++r) {
      const int co = co0 + mt * 16 + l4 * 4 + r;
      const float osc = outscale[b * COUT + co];
      float* orow = out + (((size_t)b * COUT + co) * H + h) * W;
#pragma unroll
      for (int nt = 0; nt < 4; ++nt)
        orow[nt * 16 + l15] = acc[mt][nt][r] * osc;
    }
  }
}

// ---------------------------------------------------------------------------
extern "C" void kernel_launch(void* const* d_in, const int* in_sizes, int n_in,
                              void* d_out, int out_size, void* d_ws,
                              size_t ws_size, hipStream_t stream) {
  const float* x = (const float*)d_in[0];
  const float* style = (const float*)d_in[1];
  const float* weight = (const float*)d_in[2];
  const float* style_w = (const float*)d_in[3];
  const float* style_b = (const float*)d_in[4];
  float* out = (float*)d_out;

  // workspace layout (bytes):
  //   0        s        (32768)
  //   32768    s2       (32768)
  //   65536    wsq      (1048576)
  //   1114112  outscale (32768)
  //   1146880  wt       (4718592)   packed bf16 weights (pair-interleaved)
  //   5865472  xp       (67108864)  packed bf16 x (s folded, pair-interleaved)
  char* wsb = (char*)d_ws;
  float* s = (float*)(wsb + 0);
  float* s2 = (float*)(wsb + 32768);
  float* wsq = (float*)(wsb + 65536);
  float* outscale = (float*)(wsb + 1114112);
  ushort* wt = (ushort*)(wsb + 1146880);
  ushort* xp = (ushort*)(wsb + 5865472);
  const size_t NEED = 72974336;

  hipError_t attr_ok = hipFuncSetAttribute(
      reinterpret_cast<const void*>(conv_mfma6_kernel),
      hipFuncAttributeMaxDynamicSharedMemorySize, DLDS4);

  style_mod_kernel<<<B, 512, 0, stream>>>(style, style_w, style_b, s, s2);
  pack_w_kernel<<<128, 256, 0, stream>>>(weight, wt, wsq);
  dcoef_kernel<<<B, 512, 0, stream>>>(s2, wsq, outscale);

  if (attr_ok == hipSuccess && ws_size >= NEED) {
    pack_x_kernel<<<dim3(64, 16, 16), 256, 0, stream>>>(x, s, xp);
    conv_mfma6_kernel<<<dim3(8, 8, 16), 256, DLDS4, stream>>>(wt, xp, outscale,
                                                              out);
  } else {
    conv_mfma_kernel<<<dim3(16, 8, 16), 256, 0, stream>>>(x, weight, s,
                                                          outscale, out);
  }
}